// Round 1
// baseline (1607.326 us; speedup 1.0000x reference)
//
#include <hip/hip_runtime.h>

#define NEIGHB 12
#define HIDD 128
#define TM 64
#define TNC 256
#define KB 16
#define CAP 48

// ---------------------------------------------------------------------------
// Fused (optional GBF-expansion) GEMM:  C[i, 0:256] = X[i,:] @ [Wl | Wr]^T
// MODE 0: X = xraw [N, KTOT] directly (layer 2)
// MODE 1: X = gbf(bond [N,12]) -> K = 12*40 = 480,  mu = t*8/39,  gamma=0.2
// MODE 2: X = gbf(angle [N,144]) -> K = 144*10 = 1440, mu = -1 + t*2/9
// ---------------------------------------------------------------------------
template <int MODE, int KTOT>
__global__ __launch_bounds__(256) void gemm_k(const float* __restrict__ xraw,
                                              const float* __restrict__ Wl,
                                              const float* __restrict__ Wr,
                                              float* __restrict__ C, int N) {
    constexpr int RAWC = (MODE == 2) ? 144 : 12;
    constexpr int RAWP = (MODE == 2) ? 145 : 13;  // pad: odd stride, conflict-free
    constexpr int XP = TM + 4;                    // 68
    constexpr int WP = TNC + 4;                   // 260

    __shared__ float xt[KB][XP];
    __shared__ float wt[KB][WP];
    __shared__ float raw[(MODE != 0) ? TM : 1][(MODE != 0) ? RAWP : 1];

    const int tid = threadIdx.x;
    const int iBase = blockIdx.x * TM;
    const int tr = tid >> 5;  // 0..7  (rows)
    const int tc = tid & 31;  // 0..31 (cols)

    if (MODE != 0) {
        for (int idx = tid; idx < TM * RAWC; idx += 256) {
            int r = idx / RAWC, c = idx - r * RAWC;
            int gi = min(iBase + r, N - 1);
            raw[r][c] = xraw[(size_t)gi * RAWC + c];
        }
    }

    float acc[8][8];
#pragma unroll
    for (int a = 0; a < 8; ++a)
#pragma unroll
        for (int b = 0; b < 8; ++b) acc[a][b] = 0.f;

    for (int kc = 0; kc < KTOT; kc += KB) {
        __syncthreads();
        // ---- stage X tile (transposed: xt[k][m]) ----
        if (MODE == 0) {
            int a = tid >> 2;            // row 0..63
            int b4 = (tid & 3) << 2;     // k offset 0,4,8,12
            int gi = min(iBase + a, N - 1);
            float4 v = *reinterpret_cast<const float4*>(xraw + (size_t)gi * KTOT + kc + b4);
            xt[b4 + 0][a] = v.x;
            xt[b4 + 1][a] = v.y;
            xt[b4 + 2][a] = v.z;
            xt[b4 + 3][a] = v.w;
        } else {
            constexpr int SUB = (MODE == 2) ? 10 : 40;
            const float mu0 = (MODE == 2) ? -1.0f : 0.0f;
            const float dmu = (MODE == 2) ? (2.0f / 9.0f) : (8.0f / 39.0f);
#pragma unroll
            for (int q = 0; q < 4; ++q) {
                int idx = tid + 256 * q;
                int m = idx & 63;     // lane-consecutive rows -> conflict-free
                int kk = idx >> 6;    // 0..15
                int k = kc + kk;
                int j = k / SUB;
                int t = k - j * SUB;
                float diff = raw[m][j] - (mu0 + (float)t * dmu);
                xt[kk][m] = __expf(-25.0f * diff * diff);  // 1/gamma^2 = 25
            }
        }
        // ---- stage W tile (wt[k][c], c<128 from Wl, else Wr) ----
#pragma unroll
        for (int q = 0; q < 4; ++q) {
            int idx = tid + 256 * q;  // float4 slot
            int c = idx >> 2;         // 0..255
            int kq = (idx & 3) << 2;
            const float* wrow =
                (c < HIDD) ? (Wl + (size_t)c * KTOT) : (Wr + (size_t)(c - HIDD) * KTOT);
            float4 v = *reinterpret_cast<const float4*>(wrow + kc + kq);
            wt[kq + 0][c] = v.x;
            wt[kq + 1][c] = v.y;
            wt[kq + 2][c] = v.z;
            wt[kq + 3][c] = v.w;
        }
        __syncthreads();
        // ---- compute: 8x8 micro-tile per thread ----
#pragma unroll
        for (int kk = 0; kk < KB; ++kk) {
            float4 xa = *reinterpret_cast<const float4*>(&xt[kk][tr * 4]);
            float4 xb = *reinterpret_cast<const float4*>(&xt[kk][tr * 4 + 32]);
            float4 wa = *reinterpret_cast<const float4*>(&wt[kk][tc * 4]);
            float4 wb = *reinterpret_cast<const float4*>(&wt[kk][tc * 4 + 128]);
            float xr[8] = {xa.x, xa.y, xa.z, xa.w, xb.x, xb.y, xb.z, xb.w};
            float wc[8] = {wa.x, wa.y, wa.z, wa.w, wb.x, wb.y, wb.z, wb.w};
#pragma unroll
            for (int a = 0; a < 8; ++a)
#pragma unroll
                for (int b = 0; b < 8; ++b) acc[a][b] = fmaf(xr[a], wc[b], acc[a][b]);
        }
    }

#pragma unroll
    for (int rb = 0; rb < 2; ++rb)
#pragma unroll
        for (int r = 0; r < 4; ++r) {
            int i = iBase + rb * 32 + tr * 4 + r;
            if (i < N) {
#pragma unroll
                for (int cb = 0; cb < 2; ++cb) {
                    float4 o = make_float4(acc[rb * 4 + r][cb * 4 + 0],
                                           acc[rb * 4 + r][cb * 4 + 1],
                                           acc[rb * 4 + r][cb * 4 + 2],
                                           acc[rb * 4 + r][cb * 4 + 3]);
                    *reinterpret_cast<float4*>(C + (size_t)i * TNC + cb * 128 + tc * 4) = o;
                }
            }
        }
}

// ---------------------------------------------------------------------------
// Reverse-adjacency bucket build: for edge e (src = e/12, dst = nbr[e])
// append src to dst's bucket. cnt[] must be zeroed beforehand.
// ---------------------------------------------------------------------------
__global__ void build_inc(const int* __restrict__ nbr, int* __restrict__ cnt,
                          int* __restrict__ inc, int nEdges) {
    int e = blockIdx.x * blockDim.x + threadIdx.x;
    if (e >= nEdges) return;
    int d = nbr[e];
    int src = e / NEIGHB;
    int pos = atomicAdd(&cnt[d], 1);
    if (pos < CAP) inc[(size_t)d * CAP + pos] = src;  // P(cnt>=48) ~ 1e-9: never
}

// ---------------------------------------------------------------------------
// O[d, t] = relu( mean_{src -> d} H[src, t] + bias[t] + H[d, 128 + t] )
// H = [hl | hr] row-major [N, 256]. 2 destinations per 256-thread block.
// ---------------------------------------------------------------------------
__global__ __launch_bounds__(256) void agg_relu(const float* __restrict__ H,
                                                const int* __restrict__ cnt,
                                                const int* __restrict__ inc,
                                                const float* __restrict__ bias,
                                                float* __restrict__ O, int N) {
    int d = blockIdx.x * 2 + (threadIdx.x >> 7);
    int t = threadIdx.x & 127;
    if (d >= N) return;
    int c = cnt[d];
    int cc = min(c, CAP);
    const int* lst = inc + (size_t)d * CAP;
    float s = 0.f;
    for (int e = 0; e < cc; ++e) {
        int src = lst[e];
        s += H[(size_t)src * TNC + t];
    }
    float agg = s / (float)max(c, 1);
    float v = agg + bias[t] + H[(size_t)d * TNC + HIDD + t];
    O[(size_t)d * HIDD + t] = fmaxf(v, 0.f);
}

// ---------------------------------------------------------------------------
// Per-crystal mean pool over concat(bo2, ao2) then 2-class FC.
// One block per crystal; thread t owns pooled dim t.
// ---------------------------------------------------------------------------
__global__ __launch_bounds__(256) void pool_fc(const float* __restrict__ bo,
                                               const float* __restrict__ ao,
                                               const int* __restrict__ crys,
                                               const float* __restrict__ Wfc,
                                               const float* __restrict__ bfc,
                                               float* __restrict__ out) {
    __shared__ float red0[256];
    __shared__ float red1[256];
    int b = blockIdx.x;
    int t = threadIdx.x;
    int s0 = crys[b * 2 + 0];
    int s1 = crys[b * 2 + 1];
    const float* src = (t < HIDD) ? bo : ao;
    int col = t & (HIDD - 1);
    float s = 0.f;
    for (int i = s0; i < s1; ++i) s += src[(size_t)i * HIDD + col];
    float pooled = s / (float)(s1 - s0);
    red0[t] = pooled * Wfc[t];        // Wfc[0][t]
    red1[t] = pooled * Wfc[256 + t];  // Wfc[1][t]
    __syncthreads();
    for (int off = 128; off >= 1; off >>= 1) {
        if (t < off) {
            red0[t] += red0[t + off];
            red1[t] += red1[t + off];
        }
        __syncthreads();
    }
    if (t == 0) {
        out[b * 2 + 0] = red0[0] + bfc[0];
        out[b * 2 + 1] = red1[0] + bfc[1];
    }
}

// ---------------------------------------------------------------------------
extern "C" void kernel_launch(void* const* d_in, const int* in_sizes, int n_in,
                              void* d_out, int out_size, void* d_ws, size_t ws_size,
                              hipStream_t stream) {
    const float* bond = (const float*)d_in[0];    // [N,12]
    const float* angle = (const float*)d_in[1];   // [N,144]
    const int* nbr = (const int*)d_in[3];         // [N,12]
    const int* crys = (const int*)d_in[4];        // [B,2]
    const float* W1b = (const float*)d_in[5];
    const float* b1b = (const float*)d_in[6];
    const float* W1br = (const float*)d_in[7];
    const float* W1a = (const float*)d_in[8];
    const float* b1a = (const float*)d_in[9];
    const float* W1ar = (const float*)d_in[10];
    const float* W2b = (const float*)d_in[11];
    const float* b2b = (const float*)d_in[12];
    const float* W2br = (const float*)d_in[13];
    const float* W2a = (const float*)d_in[14];
    const float* b2a = (const float*)d_in[15];
    const float* W2ar = (const float*)d_in[16];
    const float* Wfc = (const float*)d_in[17];
    const float* bfc = (const float*)d_in[18];
    float* out = (float*)d_out;

    const int N = in_sizes[2];       // 50000 (species count)
    const int B = in_sizes[4] / 2;   // 500
    const int nEdges = N * NEIGHB;   // 600000

    // ---- workspace carve (bytes) ----
    char* w = (char*)d_ws;
    float* H = (float*)(w);                                   // [N,256]  51.2 MB
    float* bo = (float*)(w + (size_t)N * 256 * 4);            // [N,128]  25.6 MB
    float* ao = (float*)(w + (size_t)N * 384 * 4);
    float* bo2 = (float*)(w + (size_t)N * 512 * 4);
    float* ao2 = (float*)(w + (size_t)N * 640 * 4);
    int* cnt = (int*)(w + (size_t)N * 768 * 4);               // [N]
    int* inc = (int*)(w + (size_t)N * 769 * 4);               // [N,CAP]  9.6 MB
    // total = N*(769 + 48)*4 = ~163.4 MB

    hipMemsetAsync(cnt, 0, (size_t)N * 4, stream);
    build_inc<<<(nEdges + 255) / 256, 256, 0, stream>>>(nbr, cnt, inc, nEdges);

    const int gBlocks = (N + TM - 1) / TM;  // 782

    // layer 1 bond
    gemm_k<1, 480><<<gBlocks, 256, 0, stream>>>(bond, W1b, W1br, H, N);
    agg_relu<<<(N + 1) / 2, 256, 0, stream>>>(H, cnt, inc, b1b, bo, N);
    // layer 1 angle
    gemm_k<2, 1440><<<gBlocks, 256, 0, stream>>>(angle, W1a, W1ar, H, N);
    agg_relu<<<(N + 1) / 2, 256, 0, stream>>>(H, cnt, inc, b1a, ao, N);
    // layer 2 bond
    gemm_k<0, 128><<<gBlocks, 256, 0, stream>>>(bo, W2b, W2br, H, N);
    agg_relu<<<(N + 1) / 2, 256, 0, stream>>>(H, cnt, inc, b2b, bo2, N);
    // layer 2 angle
    gemm_k<0, 128><<<gBlocks, 256, 0, stream>>>(ao, W2a, W2ar, H, N);
    agg_relu<<<(N + 1) / 2, 256, 0, stream>>>(H, cnt, inc, b2a, ao2, N);
    // pool + fc
    pool_fc<<<B, 256, 0, stream>>>(bo2, ao2, crys, Wfc, bfc, out);
}

// Round 2
// 806.179 us; speedup vs baseline: 1.9938x; 1.9938x over previous
//
#include <hip/hip_runtime.h>

#define NEIGHB 12
#define HIDD 128
#define CAP 40

typedef _Float16 half8 __attribute__((ext_vector_type(8)));
typedef float f32x4 __attribute__((ext_vector_type(4)));

// ---------------------------------------------------------------------------
// W pre-convert: Wl[128][K] , Wr[128][K] f32 -> Wt[256][Kp] f16, zero-padded.
// ---------------------------------------------------------------------------
__global__ void cvt_w(const float* __restrict__ Wl, const float* __restrict__ Wr,
                      _Float16* __restrict__ out, int K, int Kp) {
    int idx = blockIdx.x * 256 + threadIdx.x;
    if (idx >= 256 * Kp) return;
    int n = idx / Kp, k = idx - n * Kp;
    float v = 0.f;
    if (k < K) v = (n < HIDD) ? Wl[(size_t)n * K + k] : Wr[(size_t)(n - HIDD) * K + k];
    out[idx] = (_Float16)v;
}

// ---------------------------------------------------------------------------
// MFMA GEMM: C[i, 0:256] = X[i,:] @ Wt^T   (Wt = [Wl|Wr] rows, f16, K padded)
// MODE 0: X = xraw [N, KTOT] f32
// MODE 1: X = gbf(bond [N,12])  K=480,  SUB=40, mu = t*8/39,  1/g^2 = 25
// MODE 2: X = gbf(angle [N,144]) K=1440, SUB=10, mu = -1+t*2/9, 1/g^2 = 25
// Block: 256 thr / 4 waves; block tile 64(M) x 256(N); wave tile 64x64; BK=64.
// LDS XOR-swizzle: 16B granule g stored at g ^ (row & 7)  (conflict-floor for
// both b128 writes and MFMA fragment b128 reads).
// ---------------------------------------------------------------------------
template <int MODE, int KTOT, int KP>
__global__ __launch_bounds__(256) void gemm_f16(const float* __restrict__ xraw,
                                                const _Float16* __restrict__ Wt,
                                                float* __restrict__ C, int N) {
    constexpr int SUB = (MODE == 2) ? 10 : 40;
    constexpr int RAWC = (MODE == 2) ? 144 : 12;
    constexpr float MU0 = (MODE == 2) ? -1.0f : 0.0f;
    constexpr float DMU = (MODE == 2) ? (2.0f / 9.0f) : (8.0f / 39.0f);

    __shared__ __align__(16) _Float16 As[64 * 64];
    __shared__ __align__(16) _Float16 Bs[256 * 64];

    const int tid = threadIdx.x;
    const int lane = tid & 63;
    const int wave = tid >> 6;  // 0..3 -> output col block (64 wide)
    const int iBase = blockIdx.x * 64;

    f32x4 acc[4][4];
#pragma unroll
    for (int a = 0; a < 4; ++a)
#pragma unroll
        for (int b = 0; b < 4; ++b)
#pragma unroll
            for (int r = 0; r < 4; ++r) acc[a][b][r] = 0.f;

    for (int kc = 0; kc < KP; kc += 64) {
        __syncthreads();
        // ---- stage A tile [64][64] f16: 512 granules of 8, 2 per thread ----
#pragma unroll
        for (int q = 0; q < 2; ++q) {
            int idx = tid + 256 * q;
            int m = idx >> 3;  // 0..63
            int g = idx & 7;
            int gi = min(iBase + m, N - 1);
            half8 v;
            if (MODE == 0) {
                const float* p = xraw + (size_t)gi * KTOT + kc + g * 8;
                float4 u0 = *reinterpret_cast<const float4*>(p);
                float4 u1 = *reinterpret_cast<const float4*>(p + 4);
                v[0] = (_Float16)u0.x; v[1] = (_Float16)u0.y;
                v[2] = (_Float16)u0.z; v[3] = (_Float16)u0.w;
                v[4] = (_Float16)u1.x; v[5] = (_Float16)u1.y;
                v[6] = (_Float16)u1.z; v[7] = (_Float16)u1.w;
            } else {
                int k0 = kc + g * 8;
                if (k0 < KTOT) {  // KTOT % 8 == 0: granule fully in-range
                    int j0 = k0 / SUB;
                    int t0 = k0 - j0 * SUB;
                    const float* rr = xraw + (size_t)gi * RAWC;
                    float r0 = rr[j0];
                    float r1 = (t0 + 7 >= SUB) ? rr[j0 + 1] : r0;  // j0+1 < RAWC guaranteed
#pragma unroll
                    for (int e = 0; e < 8; ++e) {
                        int t = t0 + e;
                        bool c2 = (t >= SUB);
                        float rv = c2 ? r1 : r0;
                        float mu = MU0 + (float)(c2 ? t - SUB : t) * DMU;
                        float d = rv - mu;
                        v[e] = (_Float16)__expf(-25.f * d * d);
                    }
                } else {
#pragma unroll
                    for (int e = 0; e < 8; ++e) v[e] = (_Float16)0.f;
                }
            }
            *reinterpret_cast<half8*>(As + m * 64 + ((g ^ (m & 7)) << 3)) = v;
        }
        // ---- stage B tile [256][64] f16: 2048 granules, 8 per thread ----
#pragma unroll
        for (int q = 0; q < 8; ++q) {
            int idx = tid + 256 * q;
            int n = idx >> 3;  // 0..255
            int g = idx & 7;
            half8 v = *reinterpret_cast<const half8*>(Wt + (size_t)n * KP + kc + g * 8);
            *reinterpret_cast<half8*>(Bs + n * 64 + ((g ^ (n & 7)) << 3)) = v;
        }
        __syncthreads();
        // ---- compute: 2 sub-steps of K=32, 16 MFMA each ----
#pragma unroll
        for (int s = 0; s < 2; ++s) {
            int cg = s * 4 + (lane >> 4);  // k-granule index 0..7
            half8 af[4], bf[4];
#pragma unroll
            for (int a = 0; a < 4; ++a) {
                int m = a * 16 + (lane & 15);
                af[a] = *reinterpret_cast<const half8*>(As + m * 64 + ((cg ^ (m & 7)) << 3));
            }
#pragma unroll
            for (int b = 0; b < 4; ++b) {
                int n = wave * 64 + b * 16 + (lane & 15);
                bf[b] = *reinterpret_cast<const half8*>(Bs + n * 64 + ((cg ^ (n & 7)) << 3));
            }
#pragma unroll
            for (int a = 0; a < 4; ++a)
#pragma unroll
                for (int b = 0; b < 4; ++b)
                    acc[a][b] = __builtin_amdgcn_mfma_f32_16x16x32_f16(af[a], bf[b], acc[a][b], 0, 0, 0);
        }
    }

    // ---- epilogue: D lane layout col = lane&15, row = (lane>>4)*4 + r ----
#pragma unroll
    for (int a = 0; a < 4; ++a) {
        int mrel = a * 16 + ((lane >> 4) << 2);
#pragma unroll
        for (int r = 0; r < 4; ++r) {
            int m = iBase + mrel + r;
            if (m < N) {
#pragma unroll
                for (int b = 0; b < 4; ++b) {
                    int n = wave * 64 + b * 16 + (lane & 15);
                    C[(size_t)m * 256 + n] = acc[a][b][r];
                }
            }
        }
    }
}

// ---------------------------------------------------------------------------
// Reverse-adjacency bucket build.
// ---------------------------------------------------------------------------
__global__ void build_inc(const int* __restrict__ nbr, int* __restrict__ cnt,
                          int* __restrict__ inc, int nEdges) {
    int e = blockIdx.x * blockDim.x + threadIdx.x;
    if (e >= nEdges) return;
    int d = nbr[e];
    int src = e / NEIGHB;
    int pos = atomicAdd(&cnt[d], 1);
    if (pos < CAP) inc[(size_t)d * CAP + pos] = src;  // P(overflow) ~ 1e-10
}

// ---------------------------------------------------------------------------
// O[d, t] = relu( mean_{src -> d} H[src, t] + bias[t] + H[d, 128 + t] )
// ---------------------------------------------------------------------------
__global__ __launch_bounds__(256) void agg_relu(const float* __restrict__ H,
                                                const int* __restrict__ cnt,
                                                const int* __restrict__ inc,
                                                const float* __restrict__ bias,
                                                float* __restrict__ O, int N) {
    int d = blockIdx.x * 2 + (threadIdx.x >> 7);
    int t = threadIdx.x & 127;
    if (d >= N) return;
    int c = cnt[d];
    int cc = min(c, CAP);
    const int* lst = inc + (size_t)d * CAP;
    float s = 0.f;
    for (int e = 0; e < cc; ++e) {
        int src = lst[e];
        s += H[(size_t)src * 256 + t];
    }
    float agg = s / (float)max(c, 1);
    float v = agg + bias[t] + H[(size_t)d * 256 + HIDD + t];
    O[(size_t)d * HIDD + t] = fmaxf(v, 0.f);
}

// ---------------------------------------------------------------------------
// Per-crystal mean pool over concat(bo2, ao2) then 2-class FC.
// ---------------------------------------------------------------------------
__global__ __launch_bounds__(256) void pool_fc(const float* __restrict__ bo,
                                               const float* __restrict__ ao,
                                               const int* __restrict__ crys,
                                               const float* __restrict__ Wfc,
                                               const float* __restrict__ bfc,
                                               float* __restrict__ out) {
    __shared__ float red0[256];
    __shared__ float red1[256];
    int b = blockIdx.x;
    int t = threadIdx.x;
    int s0 = crys[b * 2 + 0];
    int s1 = crys[b * 2 + 1];
    const float* src = (t < HIDD) ? bo : ao;
    int col = t & (HIDD - 1);
    float s = 0.f;
    for (int i = s0; i < s1; ++i) s += src[(size_t)i * HIDD + col];
    float pooled = s / (float)(s1 - s0);
    red0[t] = pooled * Wfc[t];
    red1[t] = pooled * Wfc[256 + t];
    __syncthreads();
    for (int off = 128; off >= 1; off >>= 1) {
        if (t < off) {
            red0[t] += red0[t + off];
            red1[t] += red1[t + off];
        }
        __syncthreads();
    }
    if (t == 0) {
        out[b * 2 + 0] = red0[0] + bfc[0];
        out[b * 2 + 1] = red1[0] + bfc[1];
    }
}

// ---------------------------------------------------------------------------
extern "C" void kernel_launch(void* const* d_in, const int* in_sizes, int n_in,
                              void* d_out, int out_size, void* d_ws, size_t ws_size,
                              hipStream_t stream) {
    const float* bond = (const float*)d_in[0];
    const float* angle = (const float*)d_in[1];
    const int* nbr = (const int*)d_in[3];
    const int* crys = (const int*)d_in[4];
    const float* W1b = (const float*)d_in[5];
    const float* b1b = (const float*)d_in[6];
    const float* W1br = (const float*)d_in[7];
    const float* W1a = (const float*)d_in[8];
    const float* b1a = (const float*)d_in[9];
    const float* W1ar = (const float*)d_in[10];
    const float* W2b = (const float*)d_in[11];
    const float* b2b = (const float*)d_in[12];
    const float* W2br = (const float*)d_in[13];
    const float* W2a = (const float*)d_in[14];
    const float* b2a = (const float*)d_in[15];
    const float* W2ar = (const float*)d_in[16];
    const float* Wfc = (const float*)d_in[17];
    const float* bfc = (const float*)d_in[18];
    float* out = (float*)d_out;

    const int N = in_sizes[2];      // 50000
    const int B = in_sizes[4] / 2;  // 500
    const int nEdges = N * NEIGHB;

    // ---- workspace carve ----
    char* w = (char*)d_ws;
    float* H = (float*)(w);                             // [N,256]
    float* bo = (float*)(w + (size_t)N * 256 * 4);
    float* ao = (float*)(w + (size_t)N * 384 * 4);
    float* bo2 = (float*)(w + (size_t)N * 512 * 4);
    float* ao2 = (float*)(w + (size_t)N * 640 * 4);
    int* cnt = (int*)(w + (size_t)N * 768 * 4);
    int* inc = (int*)(w + (size_t)N * 769 * 4);         // [N,CAP]
    char* wf = w + (size_t)N * (769 + CAP) * 4;         // f16 weight area (~1.1MB)
    _Float16* W1bp = (_Float16*)(wf);                   // [256][512]
    _Float16* W1ap = (_Float16*)(wf + 262144);          // [256][1472]
    _Float16* W2bp = (_Float16*)(wf + 262144 + 753664); // [256][128]
    _Float16* W2ap = (_Float16*)(wf + 262144 + 753664 + 65536);

    hipMemsetAsync(cnt, 0, (size_t)N * 4, stream);
    build_inc<<<(nEdges + 255) / 256, 256, 0, stream>>>(nbr, cnt, inc, nEdges);

    cvt_w<<<(256 * 512 + 255) / 256, 256, 0, stream>>>(W1b, W1br, W1bp, 480, 512);
    cvt_w<<<(256 * 1472 + 255) / 256, 256, 0, stream>>>(W1a, W1ar, W1ap, 1440, 1472);
    cvt_w<<<(256 * 128 + 255) / 256, 256, 0, stream>>>(W2b, W2br, W2bp, 128, 128);
    cvt_w<<<(256 * 128 + 255) / 256, 256, 0, stream>>>(W2a, W2ar, W2ap, 128, 128);

    const int gB = (N + 63) / 64;  // 782

    gemm_f16<1, 480, 512><<<gB, 256, 0, stream>>>(bond, W1bp, H, N);
    agg_relu<<<(N + 1) / 2, 256, 0, stream>>>(H, cnt, inc, b1b, bo, N);
    gemm_f16<2, 1440, 1472><<<gB, 256, 0, stream>>>(angle, W1ap, H, N);
    agg_relu<<<(N + 1) / 2, 256, 0, stream>>>(H, cnt, inc, b1a, ao, N);
    gemm_f16<0, 128, 128><<<gB, 256, 0, stream>>>(bo, W2bp, H, N);
    agg_relu<<<(N + 1) / 2, 256, 0, stream>>>(H, cnt, inc, b2b, bo2, N);
    gemm_f16<0, 128, 128><<<gB, 256, 0, stream>>>(ao, W2ap, H, N);
    agg_relu<<<(N + 1) / 2, 256, 0, stream>>>(H, cnt, inc, b2a, ao2, N);

    pool_fc<<<B, 256, 0, stream>>>(bo2, ao2, crys, Wfc, bfc, out);
}

// Round 3
// 555.514 us; speedup vs baseline: 2.8934x; 1.4512x over previous
//
#include <hip/hip_runtime.h>

#define NEIGHB 12
#define HIDD 128
#define CAP 40

typedef _Float16 half8 __attribute__((ext_vector_type(8)));
typedef _Float16 half4 __attribute__((ext_vector_type(4)));
typedef float f32x4 __attribute__((ext_vector_type(4)));

// ---------------------------------------------------------------------------
// W pre-convert: Wl[128][K], Wr[128][K] f32 -> Wt[256][Kp] f16 zero-padded.
// ---------------------------------------------------------------------------
__global__ void cvt_w(const float* __restrict__ Wl, const float* __restrict__ Wr,
                      _Float16* __restrict__ out, int K, int Kp) {
    int idx = blockIdx.x * 256 + threadIdx.x;
    if (idx >= 256 * Kp) return;
    int n = idx / Kp, k = idx - n * Kp;
    float v = 0.f;
    if (k < K) v = (n < HIDD) ? Wl[(size_t)n * K + k] : Wr[(size_t)(n - HIDD) * K + k];
    out[idx] = (_Float16)v;
}

// ---------------------------------------------------------------------------
// Bond GBF expansion: bond[N,12] f32 -> feat[N,512] f16 (K=480 + pad).
// mu_t = t*8/39, 1/gamma^2 = 25. One granule of 8 per thread.
// ---------------------------------------------------------------------------
__global__ __launch_bounds__(256) void bond_exp(const float* __restrict__ bond,
                                                _Float16* __restrict__ feat, int N) {
    int idx = blockIdx.x * 256 + threadIdx.x;
    int i = idx >> 6, g = idx & 63;
    if (i >= N) return;
    int k0 = g * 8;
    half8 v;
    if (k0 < 480) {
        int j0 = k0 / 40;
        int t0 = k0 - j0 * 40;
        const float* rr = bond + (size_t)i * 12;
        float r0 = rr[j0];
        float r1 = (t0 + 7 >= 40) ? rr[j0 + 1] : r0;
#pragma unroll
        for (int e = 0; e < 8; ++e) {
            int t = t0 + e;
            bool c2 = (t >= 40);
            float d = (c2 ? r1 : r0) - (float)(c2 ? t - 40 : t) * (8.0f / 39.0f);
            v[e] = (_Float16)__expf(-25.f * d * d);
        }
    } else {
#pragma unroll
        for (int e = 0; e < 8; ++e) v[e] = (_Float16)0.f;
    }
    *reinterpret_cast<half8*>(feat + (size_t)i * 512 + k0) = v;
}

// ---------------------------------------------------------------------------
// Angle GBF expansion: angle[rows,144] f32 -> feat[rows,1472] f16 (K=1440+pad).
// mu_t = -1 + t*2/9. One block per row; thread g owns granule of 8.
// ---------------------------------------------------------------------------
__global__ __launch_bounds__(256) void angle_exp(const float* __restrict__ angle,
                                                 _Float16* __restrict__ feat, int rows) {
    __shared__ float rawr[144];
    int i = blockIdx.x;
    int g = threadIdx.x;
    if (g < 144) rawr[g] = angle[(size_t)i * 144 + g];
    __syncthreads();
    if (g >= 184) return;
    int k0 = g * 8;
    half8 v;
    if (k0 < 1440) {
        int j0 = k0 / 10;
        int t0 = k0 - j0 * 10;
        float r0 = rawr[j0];
        float r1 = (t0 + 7 >= 10 && j0 + 1 < 144) ? rawr[j0 + 1] : r0;
#pragma unroll
        for (int e = 0; e < 8; ++e) {
            int t = t0 + e;
            bool c2 = (t >= 10);
            float d = (c2 ? r1 : r0) - (-1.0f + (float)(c2 ? t - 10 : t) * (2.0f / 9.0f));
            v[e] = (_Float16)__expf(-25.f * d * d);
        }
    } else {
#pragma unroll
        for (int e = 0; e < 8; ++e) v[e] = (_Float16)0.f;
    }
    *reinterpret_cast<half8*>(feat + (size_t)i * 1472 + k0) = v;
}

// ---------------------------------------------------------------------------
// MFMA GEMM: C[i, 0:256] f16 = A[i,:] f16 @ Wt^T (Wt=[Wl|Wr] f16 [256][KP]).
// Block 256 thr / 4 waves; tile 64(M) x 256(N); wave tile 64x64; BK=64.
// LDS XOR swizzle: granule g stored at g ^ (row & 7).
// ---------------------------------------------------------------------------
template <int KP>
__global__ __launch_bounds__(256) void gemm_f16(const _Float16* __restrict__ A,
                                                const _Float16* __restrict__ Wt,
                                                _Float16* __restrict__ C, int rows) {
    __shared__ __align__(16) _Float16 As[64 * 64];
    __shared__ __align__(16) _Float16 Bs[256 * 64];

    const int tid = threadIdx.x;
    const int lane = tid & 63;
    const int wave = tid >> 6;
    const int iBase = blockIdx.x * 64;

    f32x4 acc[4][4];
#pragma unroll
    for (int a = 0; a < 4; ++a)
#pragma unroll
        for (int b = 0; b < 4; ++b)
#pragma unroll
            for (int r = 0; r < 4; ++r) acc[a][b][r] = 0.f;

    for (int kc = 0; kc < KP; kc += 64) {
        __syncthreads();
#pragma unroll
        for (int q = 0; q < 2; ++q) {
            int idx = tid + 256 * q;
            int m = idx >> 3, g = idx & 7;
            int gi = min(iBase + m, rows - 1);
            half8 v = *reinterpret_cast<const half8*>(A + (size_t)gi * KP + kc + g * 8);
            *reinterpret_cast<half8*>(As + m * 64 + ((g ^ (m & 7)) << 3)) = v;
        }
#pragma unroll
        for (int q = 0; q < 8; ++q) {
            int idx = tid + 256 * q;
            int n = idx >> 3, g = idx & 7;
            half8 v = *reinterpret_cast<const half8*>(Wt + (size_t)n * KP + kc + g * 8);
            *reinterpret_cast<half8*>(Bs + n * 64 + ((g ^ (n & 7)) << 3)) = v;
        }
        __syncthreads();
#pragma unroll
        for (int s = 0; s < 2; ++s) {
            int cg = s * 4 + (lane >> 4);
            half8 af[4], bf[4];
#pragma unroll
            for (int a = 0; a < 4; ++a) {
                int m = a * 16 + (lane & 15);
                af[a] = *reinterpret_cast<const half8*>(As + m * 64 + ((cg ^ (m & 7)) << 3));
            }
#pragma unroll
            for (int b = 0; b < 4; ++b) {
                int n = wave * 64 + b * 16 + (lane & 15);
                bf[b] = *reinterpret_cast<const half8*>(Bs + n * 64 + ((cg ^ (n & 7)) << 3));
            }
#pragma unroll
            for (int a = 0; a < 4; ++a)
#pragma unroll
                for (int b = 0; b < 4; ++b)
                    acc[a][b] = __builtin_amdgcn_mfma_f32_16x16x32_f16(af[a], bf[b], acc[a][b], 0, 0, 0);
        }
    }

#pragma unroll
    for (int a = 0; a < 4; ++a) {
        int mrel = a * 16 + ((lane >> 4) << 2);
#pragma unroll
        for (int r = 0; r < 4; ++r) {
            int m = iBase + mrel + r;
            if (m < rows) {
#pragma unroll
                for (int b = 0; b < 4; ++b) {
                    int n = wave * 64 + b * 16 + (lane & 15);
                    C[(size_t)m * 256 + n] = (_Float16)acc[a][b][r];
                }
            }
        }
    }
}

// ---------------------------------------------------------------------------
// Reverse-adjacency bucket build.
// ---------------------------------------------------------------------------
__global__ void build_inc(const int* __restrict__ nbr, int* __restrict__ cnt,
                          int* __restrict__ inc, int nEdges) {
    int e = blockIdx.x * blockDim.x + threadIdx.x;
    if (e >= nEdges) return;
    int d = nbr[e];
    int src = e / NEIGHB;
    int pos = atomicAdd(&cnt[d], 1);
    if (pos < CAP) inc[(size_t)d * CAP + pos] = src;
}

// ---------------------------------------------------------------------------
// O[d,t] f16 = relu( mean_{src->d} H[src,t] + bias[t] + H[d,128+t] ).
// H f16 [N,256]. Half-wave (32 lanes) per destination row; 4 cols per lane.
// ---------------------------------------------------------------------------
__global__ __launch_bounds__(256) void agg_relu(const _Float16* __restrict__ H,
                                                const int* __restrict__ cnt,
                                                const int* __restrict__ inc,
                                                const float* __restrict__ bias,
                                                _Float16* __restrict__ O, int N) {
    int d = blockIdx.x * 8 + (threadIdx.x >> 5);
    int c4 = (threadIdx.x & 31) * 4;
    if (d >= N) return;
    int c = cnt[d];
    int cc = min(c, CAP);
    const int* lst = inc + (size_t)d * CAP;
    float s0 = 0.f, s1 = 0.f, s2 = 0.f, s3 = 0.f;
    for (int e = 0; e < cc; ++e) {
        int src = lst[e];
        half4 v = *reinterpret_cast<const half4*>(H + (size_t)src * 256 + c4);
        s0 += (float)v[0]; s1 += (float)v[1]; s2 += (float)v[2]; s3 += (float)v[3];
    }
    float inv = 1.f / (float)max(c, 1);
    half4 sv = *reinterpret_cast<const half4*>(H + (size_t)d * 256 + HIDD + c4);
    float4 bs = *reinterpret_cast<const float4*>(bias + c4);
    half4 o;
    o[0] = (_Float16)fmaxf(s0 * inv + bs.x + (float)sv[0], 0.f);
    o[1] = (_Float16)fmaxf(s1 * inv + bs.y + (float)sv[1], 0.f);
    o[2] = (_Float16)fmaxf(s2 * inv + bs.z + (float)sv[2], 0.f);
    o[3] = (_Float16)fmaxf(s3 * inv + bs.w + (float)sv[3], 0.f);
    *reinterpret_cast<half4*>(O + (size_t)d * HIDD + c4) = o;
}

// ---------------------------------------------------------------------------
// Per-crystal mean pool over concat(bo2, ao2) f16, then 2-class FC.
// ---------------------------------------------------------------------------
__global__ __launch_bounds__(256) void pool_fc(const _Float16* __restrict__ bo,
                                               const _Float16* __restrict__ ao,
                                               const int* __restrict__ crys,
                                               const float* __restrict__ Wfc,
                                               const float* __restrict__ bfc,
                                               float* __restrict__ out) {
    __shared__ float red0[256];
    __shared__ float red1[256];
    int b = blockIdx.x;
    int t = threadIdx.x;
    int s0 = crys[b * 2 + 0];
    int s1 = crys[b * 2 + 1];
    const _Float16* src = (t < HIDD) ? bo : ao;
    int col = t & (HIDD - 1);
    float s = 0.f;
    for (int i = s0; i < s1; ++i) s += (float)src[(size_t)i * HIDD + col];
    float pooled = s / (float)(s1 - s0);
    red0[t] = pooled * Wfc[t];
    red1[t] = pooled * Wfc[256 + t];
    __syncthreads();
    for (int off = 128; off >= 1; off >>= 1) {
        if (t < off) {
            red0[t] += red0[t + off];
            red1[t] += red1[t + off];
        }
        __syncthreads();
    }
    if (t == 0) {
        out[b * 2 + 0] = red0[0] + bfc[0];
        out[b * 2 + 1] = red1[0] + bfc[1];
    }
}

// ---------------------------------------------------------------------------
extern "C" void kernel_launch(void* const* d_in, const int* in_sizes, int n_in,
                              void* d_out, int out_size, void* d_ws, size_t ws_size,
                              hipStream_t stream) {
    const float* bond = (const float*)d_in[0];
    const float* angle = (const float*)d_in[1];
    const int* nbr = (const int*)d_in[3];
    const int* crys = (const int*)d_in[4];
    const float* W1b = (const float*)d_in[5];
    const float* b1b = (const float*)d_in[6];
    const float* W1br = (const float*)d_in[7];
    const float* W1a = (const float*)d_in[8];
    const float* b1a = (const float*)d_in[9];
    const float* W1ar = (const float*)d_in[10];
    const float* W2b = (const float*)d_in[11];
    const float* b2b = (const float*)d_in[12];
    const float* W2br = (const float*)d_in[13];
    const float* W2a = (const float*)d_in[14];
    const float* b2a = (const float*)d_in[15];
    const float* W2ar = (const float*)d_in[16];
    const float* Wfc = (const float*)d_in[17];
    const float* bfc = (const float*)d_in[18];
    float* out = (float*)d_out;

    const int N = in_sizes[2];      // 50000
    const int B = in_sizes[4] / 2;  // 500
    const int nEdges = N * NEIGHB;
    const int CH = ((N + 127) / 128) * 64;  // angle chunk rows (mult of 64)

    // ---- workspace carve (all f16 activations) ----
    char* w = (char*)d_ws;
    _Float16* featA = (_Float16*)w;                       // [CH,1472] (also featB [N,512])
    char* p = w + (size_t)CH * 1472 * 2;
    _Float16* H = (_Float16*)p;      p += (size_t)N * 256 * 2;
    _Float16* bo = (_Float16*)p;     p += (size_t)N * 128 * 2;
    _Float16* ao = (_Float16*)p;     p += (size_t)N * 128 * 2;
    _Float16* bo2 = (_Float16*)p;    p += (size_t)N * 128 * 2;
    _Float16* ao2 = (_Float16*)p;    p += (size_t)N * 128 * 2;
    int* cnt = (int*)p;              p += (size_t)N * 4;
    int* inc = (int*)p;              p += (size_t)N * CAP * 4;
    _Float16* W1bp = (_Float16*)p;   p += 256 * 512 * 2;
    _Float16* W1ap = (_Float16*)p;   p += 256 * 1472 * 2;
    _Float16* W2bp = (_Float16*)p;   p += 256 * 128 * 2;
    _Float16* W2ap = (_Float16*)p;

    hipMemsetAsync(cnt, 0, (size_t)N * 4, stream);
    build_inc<<<(nEdges + 255) / 256, 256, 0, stream>>>(nbr, cnt, inc, nEdges);

    cvt_w<<<(256 * 512 + 255) / 256, 256, 0, stream>>>(W1b, W1br, W1bp, 480, 512);
    cvt_w<<<(256 * 1472 + 255) / 256, 256, 0, stream>>>(W1a, W1ar, W1ap, 1440, 1472);
    cvt_w<<<(256 * 128 + 255) / 256, 256, 0, stream>>>(W2b, W2br, W2bp, 128, 128);
    cvt_w<<<(256 * 128 + 255) / 256, 256, 0, stream>>>(W2a, W2ar, W2ap, 128, 128);

    _Float16* featB = featA;  // bond features reuse the big region

    // ---- bond layer 1 ----
    bond_exp<<<((size_t)N * 64 + 255) / 256, 256, 0, stream>>>(bond, featB, N);
    gemm_f16<512><<<(N + 63) / 64, 256, 0, stream>>>(featB, W1bp, H, N);
    agg_relu<<<(N + 7) / 8, 256, 0, stream>>>(H, cnt, inc, b1b, bo, N);

    // ---- angle layer 1 (2 chunks reusing featA) ----
    for (int c = 0; c < 2; ++c) {
        int off = c * CH;
        int rows = min(CH, N - off);
        if (rows <= 0) break;
        angle_exp<<<rows, 256, 0, stream>>>(angle + (size_t)off * 144, featA, rows);
        gemm_f16<1472><<<(rows + 63) / 64, 256, 0, stream>>>(featA, W1ap, H + (size_t)off * 256, rows);
    }
    agg_relu<<<(N + 7) / 8, 256, 0, stream>>>(H, cnt, inc, b1a, ao, N);

    // ---- layer 2 ----
    gemm_f16<128><<<(N + 63) / 64, 256, 0, stream>>>(bo, W2bp, H, N);
    agg_relu<<<(N + 7) / 8, 256, 0, stream>>>(H, cnt, inc, b2b, bo2, N);
    gemm_f16<128><<<(N + 63) / 64, 256, 0, stream>>>(ao, W2ap, H, N);
    agg_relu<<<(N + 7) / 8, 256, 0, stream>>>(H, cnt, inc, b2a, ao2, N);

    pool_fc<<<B, 256, 0, stream>>>(bo2, ao2, crys, Wfc, bfc, out);
}

// Round 4
// 431.316 us; speedup vs baseline: 3.7266x; 1.2880x over previous
//
#include <hip/hip_runtime.h>

#define NEIGHB 12
#define HIDD 128
#define CAP 40

typedef _Float16 half8 __attribute__((ext_vector_type(8)));
typedef float f32x4 __attribute__((ext_vector_type(4)));

// ---------------------------------------------------------------------------
// One-shot weight convert: 4 pairs (Wl,Wr) f32 -> [256][Kp] f16 zero-padded.
// Block ranges: [0,512)->W1b, [512,1984)->W1a, [1984,2112)->W2b, [2112,2240)->W2a
// ---------------------------------------------------------------------------
__global__ __launch_bounds__(256) void cvt_all(
    const float* __restrict__ W1b, const float* __restrict__ W1br, _Float16* __restrict__ O1b,
    const float* __restrict__ W1a, const float* __restrict__ W1ar, _Float16* __restrict__ O1a,
    const float* __restrict__ W2b, const float* __restrict__ W2br, _Float16* __restrict__ O2b,
    const float* __restrict__ W2a, const float* __restrict__ W2ar, _Float16* __restrict__ O2a) {
    int blk = blockIdx.x;
    const float *Wl, *Wr; _Float16* out; int K, Kp, base;
    if (blk < 512)       { Wl = W1b; Wr = W1br; out = O1b; K = 480;  Kp = 512;  base = 0; }
    else if (blk < 1984) { Wl = W1a; Wr = W1ar; out = O1a; K = 1440; Kp = 1472; base = 512; }
    else if (blk < 2112) { Wl = W2b; Wr = W2br; out = O2b; K = 128;  Kp = 128;  base = 1984; }
    else                 { Wl = W2a; Wr = W2ar; out = O2a; K = 128;  Kp = 128;  base = 2112; }
    int idx = (blk - base) * 256 + threadIdx.x;
    int n = idx / Kp, k = idx - n * Kp;
    float v = 0.f;
    if (k < K) v = (n < HIDD) ? Wl[(size_t)n * K + k] : Wr[(size_t)(n - HIDD) * K + k];
    out[idx] = (_Float16)v;
}

// ---------------------------------------------------------------------------
// MFMA GEMM with fused GBF expansion.
// MODE 0: A = f16 [rows, KP] read directly.
// MODE 1: A = gbf(bond f32 [rows,12]),  K=480,  SUB=40 (granule never crosses j)
// MODE 2: A = gbf(angle f32 [rows,144]), K=1440, SUB=10 (crosses at most one j)
// Output split: waves 0-1 -> Cl[rows,128], waves 2-3 -> Cr[rows,128], f16.
// Block 256 thr / 4 waves; tile 64(M) x 256(N); wave tile 64x64; BK=64.
// LDS XOR swizzle: 16B granule g at g ^ (row & 7).
// ---------------------------------------------------------------------------
template <int MODE, int KTOT, int KP>
__global__ __launch_bounds__(256) void gemm_f16(
    const void* __restrict__ Ain, const _Float16* __restrict__ Wt,
    _Float16* __restrict__ Cl, _Float16* __restrict__ Cr, int rows) {
    constexpr int SUB  = (MODE == 2) ? 10 : 40;
    constexpr int RAWC = (MODE == 2) ? 144 : 12;
    constexpr float MU0 = (MODE == 2) ? -1.0f : 0.0f;
    constexpr float DMU = (MODE == 2) ? (2.0f / 9.0f) : (8.0f / 39.0f);

    __shared__ __align__(16) _Float16 As[64 * 64];
    __shared__ __align__(16) _Float16 Bs[256 * 64];

    const int tid = threadIdx.x;
    const int lane = tid & 63;
    const int wave = tid >> 6;
    const int iBase = blockIdx.x * 64;

    f32x4 acc[4][4];
#pragma unroll
    for (int a = 0; a < 4; ++a)
#pragma unroll
        for (int b = 0; b < 4; ++b)
#pragma unroll
            for (int r = 0; r < 4; ++r) acc[a][b][r] = 0.f;

    for (int kc = 0; kc < KP; kc += 64) {
        __syncthreads();
        // ---- stage A tile [64][64]: 512 granules, 2 per thread ----
#pragma unroll
        for (int q = 0; q < 2; ++q) {
            int idx = tid + 256 * q;
            int m = idx >> 3, g = idx & 7;
            int gi = min(iBase + m, rows - 1);
            half8 v;
            if (MODE == 0) {
                v = *reinterpret_cast<const half8*>((const _Float16*)Ain + (size_t)gi * KP + kc + g * 8);
            } else {
                int k0 = kc + g * 8;
                if (k0 < KTOT) {
                    int j0 = k0 / SUB, t0 = k0 - j0 * SUB;
                    const float* rr = (const float*)Ain + (size_t)gi * RAWC;
                    float r0 = rr[j0];
                    float r1 = (MODE == 2 && t0 + 7 >= SUB) ? rr[min(j0 + 1, RAWC - 1)] : r0;
#pragma unroll
                    for (int e2 = 0; e2 < 8; ++e2) {
                        int t = t0 + e2;
                        bool c2 = (t >= SUB);
                        float d = (c2 ? r1 : r0) - (MU0 + (float)(c2 ? t - SUB : t) * DMU);
                        v[e2] = (_Float16)__expf(-25.f * d * d);
                    }
                } else {
#pragma unroll
                    for (int e2 = 0; e2 < 8; ++e2) v[e2] = (_Float16)0.f;
                }
            }
            *reinterpret_cast<half8*>(As + m * 64 + ((g ^ (m & 7)) << 3)) = v;
        }
        // ---- stage B tile [256][64]: 2048 granules, 8 per thread ----
#pragma unroll
        for (int q = 0; q < 8; ++q) {
            int idx = tid + 256 * q;
            int n = idx >> 3, g = idx & 7;
            half8 v = *reinterpret_cast<const half8*>(Wt + (size_t)n * KP + kc + g * 8);
            *reinterpret_cast<half8*>(Bs + n * 64 + ((g ^ (n & 7)) << 3)) = v;
        }
        __syncthreads();
        // ---- compute: 2 sub-steps of K=32, 16 MFMA each ----
#pragma unroll
        for (int s = 0; s < 2; ++s) {
            int cg = s * 4 + (lane >> 4);
            half8 af[4], bf[4];
#pragma unroll
            for (int a = 0; a < 4; ++a) {
                int m = a * 16 + (lane & 15);
                af[a] = *reinterpret_cast<const half8*>(As + m * 64 + ((cg ^ (m & 7)) << 3));
            }
#pragma unroll
            for (int b = 0; b < 4; ++b) {
                int n = wave * 64 + b * 16 + (lane & 15);
                bf[b] = *reinterpret_cast<const half8*>(Bs + n * 64 + ((cg ^ (n & 7)) << 3));
            }
#pragma unroll
            for (int a = 0; a < 4; ++a)
#pragma unroll
                for (int b = 0; b < 4; ++b)
                    acc[a][b] = __builtin_amdgcn_mfma_f32_16x16x32_f16(af[a], bf[b], acc[a][b], 0, 0, 0);
        }
    }

    // ---- epilogue: col = lane&15, row = (lane>>4)*4 + r; waves 0-1 -> Cl ----
    _Float16* Cout = (wave < 2) ? Cl : Cr;
    int nBase = (wave & 1) * 64;
#pragma unroll
    for (int a = 0; a < 4; ++a) {
        int mrel = a * 16 + ((lane >> 4) << 2);
#pragma unroll
        for (int r = 0; r < 4; ++r) {
            int m = iBase + mrel + r;
            if (m < rows) {
#pragma unroll
                for (int b = 0; b < 4; ++b) {
                    int n = nBase + b * 16 + (lane & 15);
                    Cout[(size_t)m * HIDD + n] = (_Float16)acc[a][b][r];
                }
            }
        }
    }
}

// ---------------------------------------------------------------------------
// Reverse-adjacency bucket build.
// ---------------------------------------------------------------------------
__global__ void build_inc(const int* __restrict__ nbr, int* __restrict__ cnt,
                          int* __restrict__ inc, int nEdges) {
    int e = blockIdx.x * blockDim.x + threadIdx.x;
    if (e >= nEdges) return;
    int d = nbr[e];
    int src = e / NEIGHB;
    int pos = atomicAdd(&cnt[d], 1);
    if (pos < CAP) inc[(size_t)d * CAP + pos] = src;
}

// ---------------------------------------------------------------------------
// O[d,:] f16 = relu( mean_{src->d} Hl[src,:] + bias + Hr[d,:] )
// 16 lanes per row (16B each), 16 rows per 256-thread block, gather unroll x2.
// ---------------------------------------------------------------------------
__global__ __launch_bounds__(256) void agg_relu(
    const _Float16* __restrict__ Hl, const _Float16* __restrict__ Hr,
    const int* __restrict__ cnt, const int* __restrict__ inc,
    const float* __restrict__ bias, _Float16* __restrict__ O, int N) {
    int d = blockIdx.x * 16 + (threadIdx.x >> 4);
    if (d >= N) return;
    int c8 = (threadIdx.x & 15) * 8;
    int c = cnt[d];
    int cc = min(c, CAP);
    const int* lst = inc + (size_t)d * CAP;
    float s[8];
#pragma unroll
    for (int j = 0; j < 8; ++j) s[j] = 0.f;
    int e = 0;
    for (; e + 2 <= cc; e += 2) {
        int i0 = lst[e], i1 = lst[e + 1];
        half8 v0 = *reinterpret_cast<const half8*>(Hl + (size_t)i0 * HIDD + c8);
        half8 v1 = *reinterpret_cast<const half8*>(Hl + (size_t)i1 * HIDD + c8);
#pragma unroll
        for (int j = 0; j < 8; ++j) s[j] += (float)v0[j] + (float)v1[j];
    }
    if (e < cc) {
        half8 v0 = *reinterpret_cast<const half8*>(Hl + (size_t)lst[e] * HIDD + c8);
#pragma unroll
        for (int j = 0; j < 8; ++j) s[j] += (float)v0[j];
    }
    float inv = 1.f / (float)max(c, 1);
    half8 hr = *reinterpret_cast<const half8*>(Hr + (size_t)d * HIDD + c8);
    float4 b0 = *reinterpret_cast<const float4*>(bias + c8);
    float4 b1 = *reinterpret_cast<const float4*>(bias + c8 + 4);
    float bb[8] = {b0.x, b0.y, b0.z, b0.w, b1.x, b1.y, b1.z, b1.w};
    half8 o;
#pragma unroll
    for (int j = 0; j < 8; ++j)
        o[j] = (_Float16)fmaxf(s[j] * inv + bb[j] + (float)hr[j], 0.f);
    *reinterpret_cast<half8*>(O + (size_t)d * HIDD + c8) = o;
}

// ---------------------------------------------------------------------------
// Per-crystal mean pool over concat(bo2, ao2) f16, then 2-class FC.
// ---------------------------------------------------------------------------
__global__ __launch_bounds__(256) void pool_fc(const _Float16* __restrict__ bo,
                                               const _Float16* __restrict__ ao,
                                               const int* __restrict__ crys,
                                               const float* __restrict__ Wfc,
                                               const float* __restrict__ bfc,
                                               float* __restrict__ out) {
    __shared__ float red0[256];
    __shared__ float red1[256];
    int b = blockIdx.x;
    int t = threadIdx.x;
    int s0 = crys[b * 2 + 0];
    int s1 = crys[b * 2 + 1];
    const _Float16* src = (t < HIDD) ? bo : ao;
    int col = t & (HIDD - 1);
    float s = 0.f;
    for (int i = s0; i < s1; ++i) s += (float)src[(size_t)i * HIDD + col];
    float pooled = s / (float)(s1 - s0);
    red0[t] = pooled * Wfc[t];
    red1[t] = pooled * Wfc[256 + t];
    __syncthreads();
    for (int off = 128; off >= 1; off >>= 1) {
        if (t < off) {
            red0[t] += red0[t + off];
            red1[t] += red1[t + off];
        }
        __syncthreads();
    }
    if (t == 0) {
        out[b * 2 + 0] = red0[0] + bfc[0];
        out[b * 2 + 1] = red1[0] + bfc[1];
    }
}

// ---------------------------------------------------------------------------
extern "C" void kernel_launch(void* const* d_in, const int* in_sizes, int n_in,
                              void* d_out, int out_size, void* d_ws, size_t ws_size,
                              hipStream_t stream) {
    const float* bond = (const float*)d_in[0];
    const float* angle = (const float*)d_in[1];
    const int* nbr = (const int*)d_in[3];
    const int* crys = (const int*)d_in[4];
    const float* W1b = (const float*)d_in[5];
    const float* b1b = (const float*)d_in[6];
    const float* W1br = (const float*)d_in[7];
    const float* W1a = (const float*)d_in[8];
    const float* b1a = (const float*)d_in[9];
    const float* W1ar = (const float*)d_in[10];
    const float* W2b = (const float*)d_in[11];
    const float* b2b = (const float*)d_in[12];
    const float* W2br = (const float*)d_in[13];
    const float* W2a = (const float*)d_in[14];
    const float* b2a = (const float*)d_in[15];
    const float* W2ar = (const float*)d_in[16];
    const float* Wfc = (const float*)d_in[17];
    const float* bfc = (const float*)d_in[18];
    float* out = (float*)d_out;

    const int N = in_sizes[2];      // 50000
    const int B = in_sizes[4] / 2;  // 500
    const int nEdges = N * NEIGHB;

    // ---- workspace carve (~86 MB) ----
    char* p = (char*)d_ws;
    _Float16* Hl  = (_Float16*)p;  p += (size_t)N * HIDD * 2;
    _Float16* Hr  = (_Float16*)p;  p += (size_t)N * HIDD * 2;
    _Float16* bo  = (_Float16*)p;  p += (size_t)N * HIDD * 2;
    _Float16* ao  = (_Float16*)p;  p += (size_t)N * HIDD * 2;
    _Float16* bo2 = (_Float16*)p;  p += (size_t)N * HIDD * 2;
    _Float16* ao2 = (_Float16*)p;  p += (size_t)N * HIDD * 2;
    int* cnt = (int*)p;            p += (size_t)N * 4;
    int* inc = (int*)p;            p += (size_t)N * CAP * 4;
    _Float16* W1bp = (_Float16*)p; p += 256 * 512 * 2;
    _Float16* W1ap = (_Float16*)p; p += 256 * 1472 * 2;
    _Float16* W2bp = (_Float16*)p; p += 256 * 128 * 2;
    _Float16* W2ap = (_Float16*)p;

    hipMemsetAsync(cnt, 0, (size_t)N * 4, stream);
    build_inc<<<(nEdges + 255) / 256, 256, 0, stream>>>(nbr, cnt, inc, nEdges);
    cvt_all<<<2240, 256, 0, stream>>>(W1b, W1br, W1bp, W1a, W1ar, W1ap,
                                      W2b, W2br, W2bp, W2a, W2ar, W2ap);

    const int gB = (N + 63) / 64;    // 782
    const int aB = (N + 15) / 16;    // 3125

    // bond layer 1 (fused GBF)
    gemm_f16<1, 480, 512><<<gB, 256, 0, stream>>>(bond, W1bp, Hl, Hr, N);
    agg_relu<<<aB, 256, 0, stream>>>(Hl, Hr, cnt, inc, b1b, bo, N);
    // angle layer 1 (fused GBF, single launch)
    gemm_f16<2, 1440, 1472><<<gB, 256, 0, stream>>>(angle, W1ap, Hl, Hr, N);
    agg_relu<<<aB, 256, 0, stream>>>(Hl, Hr, cnt, inc, b1a, ao, N);
    // layer 2
    gemm_f16<0, 128, 128><<<gB, 256, 0, stream>>>(bo, W2bp, Hl, Hr, N);
    agg_relu<<<aB, 256, 0, stream>>>(Hl, Hr, cnt, inc, b2b, bo2, N);
    gemm_f16<0, 128, 128><<<gB, 256, 0, stream>>>(ao, W2ap, Hl, Hr, N);
    agg_relu<<<aB, 256, 0, stream>>>(Hl, Hr, cnt, inc, b2a, ao2, N);

    pool_fc<<<B, 256, 0, stream>>>(bo2, ao2, crys, Wfc, bfc, out);
}